// Round 8
// baseline (741.963 us; speedup 1.0000x reference)
//
#include <hip/hip_runtime.h>
#include <cstdint>
#include <cstddef>

#define B_ 2
#define S_ 2048
#define HID_ 1024
#define H_ 16
#define DH_ 64

typedef __attribute__((ext_vector_type(8))) short short8;
typedef __attribute__((ext_vector_type(8))) unsigned short ushort8;
typedef __attribute__((ext_vector_type(4))) unsigned short ushort4v;
typedef __attribute__((ext_vector_type(4))) float floatx4;
typedef __attribute__((ext_vector_type(4))) float float4v;

static __device__ __forceinline__ unsigned short f2bf(float f) {
  unsigned int u = __float_as_uint(f);
  u += 0x7fffu + ((u >> 16) & 1u);
  return (unsigned short)(u >> 16);
}
static __device__ __forceinline__ float bf2f(unsigned short h) {
  return __uint_as_float(((unsigned int)h) << 16);
}

// ---------------------------------------------------------------------------
// Kernel 0: conversions. (unchanged, proven round 5/7)
// ---------------------------------------------------------------------------
__global__ __launch_bounds__(256) void convert_kernel(
    const float* __restrict__ x, const float* __restrict__ w1,
    const float* __restrict__ w2, unsigned short* __restrict__ x_bf,
    unsigned short* __restrict__ w1t, unsigned short* __restrict__ w2t_hi,
    unsigned short* __restrict__ w2t_lo) {
  const int NX = B_ * S_ * HID_;
  const int NW = HID_ * HID_;
  int idx = blockIdx.x * 256 + threadIdx.x;
  if (idx < NX) {
    x_bf[idx] = f2bf(x[idx]);
  } else if (idx < NX + NW) {
    int i = idx - NX;
    int n = i >> 10, k = i & 1023;
    w1t[i] = f2bf(w1[k * HID_ + n]);
  } else if (idx < NX + 2 * NW) {
    int i = idx - NX - NW;
    int n = i >> 10, k = i & 1023;
    float v = w2[k * HID_ + n];
    unsigned short h = f2bf(v);
    w2t_hi[i] = h;
    w2t_lo[i] = f2bf(v - bf2f(h));
  }
}

// ---------------------------------------------------------------------------
// Kernel A: per-head QKV projection + bias + rotary, fp32 out. (proven r5/r7)
// ---------------------------------------------------------------------------
__global__ __launch_bounds__(256) void qkv_kernel(
    const float* __restrict__ x, const float* __restrict__ wq,
    const float* __restrict__ bq, const float* __restrict__ wk,
    const float* __restrict__ bk, const float* __restrict__ wv,
    const float* __restrict__ theta, float* __restrict__ q_f,
    float* __restrict__ k_f, float* __restrict__ v_f, int b) {
  __shared__ __align__(16) float xs[64 * 68];
  __shared__ __align__(16) float wqs[64 * 68];
  __shared__ __align__(16) float wks[64 * 68];
  __shared__ __align__(16) float wvs[64 * 68];

  int tid = threadIdx.x;
  int st = blockIdx.x, h = blockIdx.y;
  int s0 = st * 64;

#pragma unroll
  for (int i = 0; i < 4; ++i) {
    int cid = tid + i * 256;
    int r = cid >> 4, c4 = (cid & 15) * 4;
    *reinterpret_cast<float4v*>(&xs[r * 68 + c4]) =
        *reinterpret_cast<const float4v*>(x + ((size_t)(b * S_ + s0 + r)) * HID_ + h * DH_ + c4);
  }
#pragma unroll
  for (int i = 0; i < 4; ++i) {
    int cid = tid + i * 256;
    int d = cid >> 4, c4 = (cid & 15) * 4;
    *reinterpret_cast<float4v*>(&wqs[d * 68 + c4]) =
        *reinterpret_cast<const float4v*>(wq + (size_t)(h * DH_ + d) * DH_ + c4);
    *reinterpret_cast<float4v*>(&wks[d * 68 + c4]) =
        *reinterpret_cast<const float4v*>(wk + (size_t)(h * DH_ + d) * DH_ + c4);
    *reinterpret_cast<float4v*>(&wvs[d * 68 + c4]) =
        *reinterpret_cast<const float4v*>(wv + (size_t)(h * DH_ + d) * DH_ + c4);
  }
  __syncthreads();

  int rg = tid >> 3;
  int cg = tid & 7;
  int r0 = rg * 2, c0 = cg * 8;

  float aq[2][8], ak[2][8], av[2][8];
#pragma unroll
  for (int i = 0; i < 2; ++i)
#pragma unroll
    for (int j = 0; j < 8; ++j) { aq[i][j] = 0.f; ak[i][j] = 0.f; av[i][j] = 0.f; }

  for (int d = 0; d < 64; ++d) {
    float x0 = xs[(r0 + 0) * 68 + d];
    float x1 = xs[(r0 + 1) * 68 + d];
#pragma unroll
    for (int j = 0; j < 8; ++j) {
      float wqv = wqs[d * 68 + c0 + j];
      float wkv = wks[d * 68 + c0 + j];
      float wvv = wvs[d * 68 + c0 + j];
      aq[0][j] += x0 * wqv; aq[1][j] += x1 * wqv;
      ak[0][j] += x0 * wkv; ak[1][j] += x1 * wkv;
      av[0][j] += x0 * wvv; av[1][j] += x1 * wvv;
    }
  }

  float thv[8], bqv[8], bkv[8];
#pragma unroll
  for (int j = 0; j < 8; ++j) {
    thv[j] = theta[h * DH_ + c0 + j];
    bqv[j] = bq[h * DH_ + c0 + j];
    bkv[j] = bk[h * DH_ + c0 + j];
  }

#pragma unroll
  for (int i = 0; i < 2; ++i) {
    int s = s0 + r0 + i;
    size_t qbase = ((size_t)h * S_ + s) * 128;
    size_t vbase = ((size_t)h * S_ + s) * 64;
#pragma unroll
    for (int j = 0; j < 8; ++j) {
      float q = aq[i][j] + bqv[j];
      float k = ak[i][j] + bkv[j];
      float ang = (float)s * thv[j];
      float cs = cosf(ang), sn = sinf(ang);
      q_f[qbase + c0 + j] = q * cs;
      q_f[qbase + 64 + c0 + j] = q * sn;
      k_f[qbase + c0 + j] = k * cs;
      k_f[qbase + 64 + c0 + j] = k * sn;
      v_f[vbase + c0 + j] = av[i][j];
    }
  }
}

// ---------------------------------------------------------------------------
// Kernel B: hybrid retention (proven r7 structure) with perf fixes:
//  - heavy-first dispatch: qt = 31 - blockIdx.x (triangular-tail shave)
//  - Sc stride 65 -> 68 (16B-aligned float4 rows)
//  - PV phase uses float4 LDS reads: 1088 b32 -> 272 b128 per thread/tile
// Arithmetic order per acc[i] unchanged -> retn bit-identical to round 7.
// ---------------------------------------------------------------------------
__global__ __launch_bounds__(256) void retention_hybrid_kernel(
    const float* __restrict__ q_f, const float* __restrict__ k_f,
    const float* __restrict__ v_f, const float* __restrict__ gn_w,
    const float* __restrict__ gn_b, float* __restrict__ retn, int b) {
  __shared__ __align__(16) unsigned short Kh[64 * 136];   // 17 KiB
  __shared__ __align__(16) unsigned short Klo[64 * 136];  // 17 KiB
  __shared__ __align__(16) float Vl[64 * 68];             // 17 KiB (fp32)
  __shared__ __align__(16) float Sc[64 * 68];             // 17 KiB (fp32)
  __shared__ float gnred[64][8];

  int tid = threadIdx.x;
  int w = tid >> 6;
  int lane = tid & 63, ln = lane & 15, quad = lane >> 4;
  int qt = (int)(gridDim.x - 1) - (int)blockIdx.x;  // heavy blocks first
  int h = blockIdx.y;
  int s0 = qt * 64;

  const float lo_c = -6.2383246250395075f, hi_c = -3.4657359027997265f;
  float gam = 1.f - __expf(lo_c + (hi_c - lo_c) * ((float)h * (1.f / 15.f)));
  float logg = __logf(gam);

  // Q fragments (A-layout: m=ln, k=quad*8+j + 32c), split hi/lo in regs.
  int sQ = s0 + w * 16 + ln;
  const float* qrow = q_f + ((size_t)h * S_ + sQ) * 128 + quad * 8;
  short8 qh[4], ql[4];
#pragma unroll
  for (int c = 0; c < 4; ++c) {
#pragma unroll
    for (int j = 0; j < 8; ++j) {
      float qv = qrow[c * 32 + j];
      unsigned short hh = f2bf(qv);
      qh[c][j] = (short)hh;
      ql[c][j] = (short)f2bf(qv - bf2f(hh));
    }
  }

  // Phase-2 thread mapping: row r2, channel group sub (16 ch each).
  int r2 = tid >> 2;
  int sub = tid & 3;
  float acc[16];
#pragma unroll
  for (int i = 0; i < 16; ++i) acc[i] = 0.f;

  for (int kt = 0; kt <= qt; ++kt) {
    int t0 = kt * 64;
    __syncthreads();  // prev phase-2 reads of Kh/Klo/Vl/Sc done

    // stage K tile 64x128: fp32 -> split bf16
#pragma unroll
    for (int i = 0; i < 8; ++i) {
      int cid = tid + i * 256;
      int rr = cid >> 5, c4 = (cid & 31) * 4;
      float4v kv = *reinterpret_cast<const float4v*>(
          k_f + ((size_t)h * S_ + t0 + rr) * 128 + c4);
      ushort4v khv, klv;
#pragma unroll
      for (int k = 0; k < 4; ++k) {
        unsigned short hh = f2bf(kv[k]);
        khv[k] = hh;
        klv[k] = f2bf(kv[k] - bf2f(hh));
      }
      *reinterpret_cast<ushort4v*>(&Kh[rr * 136 + c4]) = khv;
      *reinterpret_cast<ushort4v*>(&Klo[rr * 136 + c4]) = klv;
    }
    // stage V tile fp32
#pragma unroll
    for (int i = 0; i < 4; ++i) {
      int cid = tid + i * 256;
      int rr = cid >> 4, c4 = (cid & 15) * 4;
      *reinterpret_cast<float4v*>(&Vl[rr * 68 + c4]) =
          *reinterpret_cast<const float4v*>(v_f + ((size_t)h * S_ + t0 + rr) * 64 + c4);
    }
    __syncthreads();

    // QK^T split-MFMA (proven r7)
    floatx4 accS[4];
#pragma unroll
    for (int ns = 0; ns < 4; ++ns) {
      floatx4 a = (floatx4){0.f, 0.f, 0.f, 0.f};
#pragma unroll
      for (int ks = 0; ks < 4; ++ks) {
        int off = (ns * 16 + ln) * 136 + ks * 32 + quad * 8;
        short8 kh = *reinterpret_cast<const short8*>(&Kh[off]);
        short8 kl = *reinterpret_cast<const short8*>(&Klo[off]);
        a = __builtin_amdgcn_mfma_f32_16x16x32_bf16(qh[ks], kh, a, 0, 0, 0);
        a = __builtin_amdgcn_mfma_f32_16x16x32_bf16(ql[ks], kh, a, 0, 0, 0);
        a = __builtin_amdgcn_mfma_f32_16x16x32_bf16(qh[ks], kl, a, 0, 0, 0);
      }
      accS[ns] = a;
    }

    // decay + causal mask on C-layout, store fp32 Sc [row][t], stride 68.
    int prow = quad * 4;
#pragma unroll
    for (int ns = 0; ns < 4; ++ns) {
      int t = t0 + ns * 16 + ln;
#pragma unroll
      for (int rr = 0; rr < 4; ++rr) {
        int s = s0 + w * 16 + prow + rr;
        int diff = s - t;
        float v = accS[ns][rr];
        Sc[(w * 16 + prow + rr) * 68 + (ns * 16 + ln)] =
            (diff >= 0) ? v * __expf((float)diff * logg) : 0.f;
      }
    }
    __syncthreads();

    // phase 2: VALU PV accumulate, float4 LDS reads.
#pragma unroll 4
    for (int tt4 = 0; tt4 < 16; ++tt4) {
      float4v sc4 = *reinterpret_cast<const float4v*>(&Sc[r2 * 68 + tt4 * 4]);
#pragma unroll
      for (int j = 0; j < 4; ++j) {
        float p = sc4[j];
        int tt = tt4 * 4 + j;
#pragma unroll
        for (int i4 = 0; i4 < 4; ++i4) {
          float4v vv = *reinterpret_cast<const float4v*>(
              &Vl[tt * 68 + sub * 16 + i4 * 4]);
          acc[i4 * 4 + 0] += p * vv[0];
          acc[i4 * 4 + 1] += p * vv[1];
          acc[i4 * 4 + 2] += p * vv[2];
          acc[i4 * 4 + 3] += p * vv[3];
        }
      }
    }
  }

  // GroupNorm epilogue (proven r5/r7)
  float psum = 0.f, psq = 0.f;
#pragma unroll
  for (int i = 0; i < 16; ++i) { psum += acc[i]; psq += acc[i] * acc[i]; }
  __syncthreads();
  gnred[r2][sub] = psum;
  gnred[r2][4 + sub] = psq;
  __syncthreads();
  float sum = gnred[r2][0] + gnred[r2][1] + gnred[r2][2] + gnred[r2][3];
  float sq = gnred[r2][4] + gnred[r2][5] + gnred[r2][6] + gnred[r2][7];
  float mean = sum * (1.f / 64.f);
  float var = sq * (1.f / 64.f) - mean * mean;
  float rstd = rsqrtf(var + 1e-5f);

  size_t obase = ((size_t)(b * S_ + s0 + r2)) * HID_ + h * DH_ + sub * 16;
#pragma unroll
  for (int i = 0; i < 16; ++i) {
    float gw = gn_w[h * DH_ + sub * 16 + i];
    float gb = gn_b[h * DH_ + sub * 16 + i];
    retn[obase + i] = (acc[i] - mean) * rstd * gw + gb;
  }
}

// ---------------------------------------------------------------------------
// GEMM 1 (gate): unchanged, proven round 5/7.
// ---------------------------------------------------------------------------
__global__ __launch_bounds__(256) void gemm_gate_kernel(
    const unsigned short* __restrict__ A, const unsigned short* __restrict__ Bt,
    const float* __restrict__ retn, unsigned short* __restrict__ pre_hi,
    unsigned short* __restrict__ pre_lo) {
  const int K = HID_;
  __shared__ __align__(16) unsigned short Al[128 * 56];
  __shared__ __align__(16) unsigned short Bl[128 * 56];

  int tid = threadIdx.x;
  int lane = tid & 63, ln = lane & 15, quad = lane >> 4;
  int w = tid >> 6, wm = w >> 1, wn = w & 1;
  int m0 = blockIdx.y * 128, n0 = blockIdx.x * 128;

  floatx4 acc[4][4];
#pragma unroll
  for (int i = 0; i < 4; ++i)
#pragma unroll
    for (int j = 0; j < 4; ++j) acc[i][j] = (floatx4){0.f, 0.f, 0.f, 0.f};

  for (int k0 = 0; k0 < K; k0 += 32) {
    __syncthreads();
#pragma unroll
    for (int i = 0; i < 2; ++i) {
      int cid = tid + i * 256;
      int r = cid >> 2, c8 = (cid & 3) * 8;
      *reinterpret_cast<ushort8*>(&Al[r * 56 + c8]) =
          *reinterpret_cast<const ushort8*>(A + (size_t)(m0 + r) * K + k0 + c8);
      *reinterpret_cast<ushort8*>(&Bl[r * 56 + c8]) =
          *reinterpret_cast<const ushort8*>(Bt + (size_t)(n0 + r) * K + k0 + c8);
    }
    __syncthreads();

    short8 af[4], bfr[4];
#pragma unroll
    for (int i = 0; i < 4; ++i) {
      af[i] = *reinterpret_cast<const short8*>(&Al[(wm * 64 + i * 16 + ln) * 56 + quad * 8]);
      bfr[i] = *reinterpret_cast<const short8*>(&Bl[(wn * 64 + i * 16 + ln) * 56 + quad * 8]);
    }
#pragma unroll
    for (int mi = 0; mi < 4; ++mi)
#pragma unroll
      for (int ni = 0; ni < 4; ++ni)
        acc[mi][ni] = __builtin_amdgcn_mfma_f32_16x16x32_bf16(af[mi], bfr[ni], acc[mi][ni], 0, 0, 0);
  }

#pragma unroll
  for (int mi = 0; mi < 4; ++mi) {
#pragma unroll
    for (int r = 0; r < 4; ++r) {
      int row = m0 + wm * 64 + mi * 16 + quad * 4 + r;
#pragma unroll
      for (int ni = 0; ni < 4; ++ni) {
        int col = n0 + wn * 64 + ni * 16 + ln;
        float g = acc[mi][ni][r];
        float val = g * (1.f / (1.f + __expf(-g))) + retn[(size_t)row * HID_ + col];
        unsigned short hh = f2bf(val);
        size_t oidx = (size_t)row * HID_ + col;
        pre_hi[oidx] = hh;
        pre_lo[oidx] = f2bf(val - bf2f(hh));
      }
    }
  }
}

// ---------------------------------------------------------------------------
// GEMM 2 (output): unchanged, proven round 5/7.
// ---------------------------------------------------------------------------
__global__ __launch_bounds__(256) void gemm_out_kernel(
    const unsigned short* __restrict__ Ah, const unsigned short* __restrict__ Alo,
    const unsigned short* __restrict__ Bth, const unsigned short* __restrict__ Btlo,
    float* __restrict__ out_f) {
  const int K = HID_;
  __shared__ __align__(16) unsigned short AhS[128 * 56];
  __shared__ __align__(16) unsigned short AlS[128 * 56];
  __shared__ __align__(16) unsigned short BhS[128 * 56];
  __shared__ __align__(16) unsigned short BlS[128 * 56];

  int tid = threadIdx.x;
  int lane = tid & 63, ln = lane & 15, quad = lane >> 4;
  int w = tid >> 6, wm = w >> 1, wn = w & 1;
  int m0 = blockIdx.y * 128, n0 = blockIdx.x * 128;

  floatx4 acc[4][4];
#pragma unroll
  for (int i = 0; i < 4; ++i)
#pragma unroll
    for (int j = 0; j < 4; ++j) acc[i][j] = (floatx4){0.f, 0.f, 0.f, 0.f};

  for (int k0 = 0; k0 < K; k0 += 32) {
    __syncthreads();
#pragma unroll
    for (int i = 0; i < 2; ++i) {
      int cid = tid + i * 256;
      int r = cid >> 2, c8 = (cid & 3) * 8;
      size_t ga = (size_t)(m0 + r) * K + k0 + c8;
      size_t gb = (size_t)(n0 + r) * K + k0 + c8;
      *reinterpret_cast<ushort8*>(&AhS[r * 56 + c8]) = *reinterpret_cast<const ushort8*>(Ah + ga);
      *reinterpret_cast<ushort8*>(&AlS[r * 56 + c8]) = *reinterpret_cast<const ushort8*>(Alo + ga);
      *reinterpret_cast<ushort8*>(&BhS[r * 56 + c8]) = *reinterpret_cast<const ushort8*>(Bth + gb);
      *reinterpret_cast<ushort8*>(&BlS[r * 56 + c8]) = *reinterpret_cast<const ushort8*>(Btlo + gb);
    }
    __syncthreads();

    short8 afh[4], afl[4], bfh[4], bfl[4];
#pragma unroll
    for (int i = 0; i < 4; ++i) {
      int ao = (wm * 64 + i * 16 + ln) * 56 + quad * 8;
      int bo = (wn * 64 + i * 16 + ln) * 56 + quad * 8;
      afh[i] = *reinterpret_cast<const short8*>(&AhS[ao]);
      afl[i] = *reinterpret_cast<const short8*>(&AlS[ao]);
      bfh[i] = *reinterpret_cast<const short8*>(&BhS[bo]);
      bfl[i] = *reinterpret_cast<const short8*>(&BlS[bo]);
    }
#pragma unroll
    for (int mi = 0; mi < 4; ++mi)
#pragma unroll
      for (int ni = 0; ni < 4; ++ni) {
        floatx4 a = acc[mi][ni];
        a = __builtin_amdgcn_mfma_f32_16x16x32_bf16(afh[mi], bfh[ni], a, 0, 0, 0);
        a = __builtin_amdgcn_mfma_f32_16x16x32_bf16(afl[mi], bfh[ni], a, 0, 0, 0);
        a = __builtin_amdgcn_mfma_f32_16x16x32_bf16(afh[mi], bfl[ni], a, 0, 0, 0);
        acc[mi][ni] = a;
      }
  }

#pragma unroll
  for (int mi = 0; mi < 4; ++mi) {
#pragma unroll
    for (int r = 0; r < 4; ++r) {
      int row = m0 + wm * 64 + mi * 16 + quad * 4 + r;
#pragma unroll
      for (int ni = 0; ni < 4; ++ni) {
        int col = n0 + wn * 64 + ni * 16 + ln;
        out_f[(size_t)row * HID_ + col] = acc[mi][ni][r];
      }
    }
  }
}

// ---------------------------------------------------------------------------
extern "C" void kernel_launch(void* const* d_in, const int* in_sizes, int n_in,
                              void* d_out, int out_size, void* d_ws,
                              size_t ws_size, hipStream_t stream) {
  (void)in_sizes; (void)n_in; (void)out_size; (void)ws_size;
  const float* x = (const float*)d_in[0];
  const float* wq = (const float*)d_in[1];
  const float* bq = (const float*)d_in[2];
  const float* wk = (const float*)d_in[3];
  const float* bk = (const float*)d_in[4];
  const float* wv = (const float*)d_in[5];
  const float* theta = (const float*)d_in[6];
  const float* gn_w = (const float*)d_in[7];
  const float* gn_b = (const float*)d_in[8];
  const float* w1 = (const float*)d_in[9];
  const float* w2 = (const float*)d_in[10];

  const size_t MB = 1024 * 1024;
  char* ws = (char*)d_ws;
  unsigned short* x_bf   = (unsigned short*)(ws + 0 * MB);    //  8 MiB
  unsigned short* w1t    = (unsigned short*)(ws + 8 * MB);    //  2 MiB
  unsigned short* w2t_hi = (unsigned short*)(ws + 10 * MB);   //  2 MiB
  unsigned short* w2t_lo = (unsigned short*)(ws + 12 * MB);   //  2 MiB
  float*          q_f    = (float*)(ws + 14 * MB);            // 16 MiB (1 batch)
  float*          k_f    = (float*)(ws + 30 * MB);            // 16 MiB
  float*          v_f    = (float*)(ws + 46 * MB);            //  8 MiB
  float*          retn   = (float*)(ws + 54 * MB);            // 16 MiB (both batches)
  unsigned short* pre_hi = (unsigned short*)(ws + 14 * MB);   //  8 MiB (alias q_f)
  unsigned short* pre_lo = (unsigned short*)(ws + 22 * MB);   //  8 MiB
  float* out = (float*)d_out;

  convert_kernel<<<dim3(24576), 256, 0, stream>>>(x, w1, w2, x_bf, w1t, w2t_hi, w2t_lo);
  for (int b = 0; b < B_; ++b) {
    qkv_kernel<<<dim3(S_ / 64, H_), 256, 0, stream>>>(
        x, wq, bq, wk, bk, wv, theta, q_f, k_f, v_f, b);
    retention_hybrid_kernel<<<dim3(S_ / 64, H_), 256, 0, stream>>>(
        q_f, k_f, v_f, gn_w, gn_b, retn, b);
  }
  gemm_gate_kernel<<<dim3(HID_ / 128, (B_ * S_) / 128), 256, 0, stream>>>(
      x_bf, w1t, retn, pre_hi, pre_lo);
  gemm_out_kernel<<<dim3(HID_ / 128, (B_ * S_) / 128), 256, 0, stream>>>(
      pre_hi, pre_lo, w2t_hi, w2t_lo, out);
}

// Round 9
// 594.762 us; speedup vs baseline: 1.2475x; 1.2475x over previous
//
#include <hip/hip_runtime.h>
#include <cstdint>
#include <cstddef>

#define B_ 2
#define S_ 2048
#define HID_ 1024
#define H_ 16
#define DH_ 64

typedef __attribute__((ext_vector_type(8))) short short8;
typedef __attribute__((ext_vector_type(8))) unsigned short ushort8;
typedef __attribute__((ext_vector_type(4))) unsigned short ushort4v;
typedef __attribute__((ext_vector_type(4))) float floatx4;
typedef __attribute__((ext_vector_type(4))) float float4v;

static __device__ __forceinline__ unsigned short f2bf(float f) {
  unsigned int u = __float_as_uint(f);
  u += 0x7fffu + ((u >> 16) & 1u);
  return (unsigned short)(u >> 16);
}
static __device__ __forceinline__ float bf2f(unsigned short h) {
  return __uint_as_float(((unsigned int)h) << 16);
}

// ---------------------------------------------------------------------------
// Kernel 0: conversions. (unchanged, proven)
// ---------------------------------------------------------------------------
__global__ __launch_bounds__(256) void convert_kernel(
    const float* __restrict__ x, const float* __restrict__ w1,
    const float* __restrict__ w2, unsigned short* __restrict__ x_bf,
    unsigned short* __restrict__ w1t, unsigned short* __restrict__ w2t_hi,
    unsigned short* __restrict__ w2t_lo) {
  const int NX = B_ * S_ * HID_;
  const int NW = HID_ * HID_;
  int idx = blockIdx.x * 256 + threadIdx.x;
  if (idx < NX) {
    x_bf[idx] = f2bf(x[idx]);
  } else if (idx < NX + NW) {
    int i = idx - NX;
    int n = i >> 10, k = i & 1023;
    w1t[i] = f2bf(w1[k * HID_ + n]);
  } else if (idx < NX + 2 * NW) {
    int i = idx - NX - NW;
    int n = i >> 10, k = i & 1023;
    float v = w2[k * HID_ + n];
    unsigned short h = f2bf(v);
    w2t_hi[i] = h;
    w2t_lo[i] = f2bf(v - bf2f(h));
  }
}

// ---------------------------------------------------------------------------
// Kernel A: per-head QKV projection + bias + rotary, fp32 out. (proven)
// ---------------------------------------------------------------------------
__global__ __launch_bounds__(256) void qkv_kernel(
    const float* __restrict__ x, const float* __restrict__ wq,
    const float* __restrict__ bq, const float* __restrict__ wk,
    const float* __restrict__ bk, const float* __restrict__ wv,
    const float* __restrict__ theta, float* __restrict__ q_f,
    float* __restrict__ k_f, float* __restrict__ v_f, int b) {
  __shared__ __align__(16) float xs[64 * 68];
  __shared__ __align__(16) float wqs[64 * 68];
  __shared__ __align__(16) float wks[64 * 68];
  __shared__ __align__(16) float wvs[64 * 68];

  int tid = threadIdx.x;
  int st = blockIdx.x, h = blockIdx.y;
  int s0 = st * 64;

#pragma unroll
  for (int i = 0; i < 4; ++i) {
    int cid = tid + i * 256;
    int r = cid >> 4, c4 = (cid & 15) * 4;
    *reinterpret_cast<float4v*>(&xs[r * 68 + c4]) =
        *reinterpret_cast<const float4v*>(x + ((size_t)(b * S_ + s0 + r)) * HID_ + h * DH_ + c4);
  }
#pragma unroll
  for (int i = 0; i < 4; ++i) {
    int cid = tid + i * 256;
    int d = cid >> 4, c4 = (cid & 15) * 4;
    *reinterpret_cast<float4v*>(&wqs[d * 68 + c4]) =
        *reinterpret_cast<const float4v*>(wq + (size_t)(h * DH_ + d) * DH_ + c4);
    *reinterpret_cast<float4v*>(&wks[d * 68 + c4]) =
        *reinterpret_cast<const float4v*>(wk + (size_t)(h * DH_ + d) * DH_ + c4);
    *reinterpret_cast<float4v*>(&wvs[d * 68 + c4]) =
        *reinterpret_cast<const float4v*>(wv + (size_t)(h * DH_ + d) * DH_ + c4);
  }
  __syncthreads();

  int rg = tid >> 3;
  int cg = tid & 7;
  int r0 = rg * 2, c0 = cg * 8;

  float aq[2][8], ak[2][8], av[2][8];
#pragma unroll
  for (int i = 0; i < 2; ++i)
#pragma unroll
    for (int j = 0; j < 8; ++j) { aq[i][j] = 0.f; ak[i][j] = 0.f; av[i][j] = 0.f; }

  for (int d = 0; d < 64; ++d) {
    float x0 = xs[(r0 + 0) * 68 + d];
    float x1 = xs[(r0 + 1) * 68 + d];
#pragma unroll
    for (int j = 0; j < 8; ++j) {
      float wqv = wqs[d * 68 + c0 + j];
      float wkv = wks[d * 68 + c0 + j];
      float wvv = wvs[d * 68 + c0 + j];
      aq[0][j] += x0 * wqv; aq[1][j] += x1 * wqv;
      ak[0][j] += x0 * wkv; ak[1][j] += x1 * wkv;
      av[0][j] += x0 * wvv; av[1][j] += x1 * wvv;
    }
  }

  float thv[8], bqv[8], bkv[8];
#pragma unroll
  for (int j = 0; j < 8; ++j) {
    thv[j] = theta[h * DH_ + c0 + j];
    bqv[j] = bq[h * DH_ + c0 + j];
    bkv[j] = bk[h * DH_ + c0 + j];
  }

#pragma unroll
  for (int i = 0; i < 2; ++i) {
    int s = s0 + r0 + i;
    size_t qbase = ((size_t)h * S_ + s) * 128;
    size_t vbase = ((size_t)h * S_ + s) * 64;
#pragma unroll
    for (int j = 0; j < 8; ++j) {
      float q = aq[i][j] + bqv[j];
      float k = ak[i][j] + bkv[j];
      float ang = (float)s * thv[j];
      float cs = cosf(ang), sn = sinf(ang);
      q_f[qbase + c0 + j] = q * cs;
      q_f[qbase + 64 + c0 + j] = q * sn;
      k_f[qbase + c0 + j] = k * cs;
      k_f[qbase + 64 + c0 + j] = k * sn;
      v_f[vbase + c0 + j] = av[i][j];
    }
  }
}

// ---------------------------------------------------------------------------
// Kernel B: retention v3 — proven QK-MFMA half (r7) + NEW PV-MFMA built from
// proven parts: P A-frags read fp32 from Sc and hi/lo split in registers
// (same pattern as proven Q-frag load; no bf16 P LDS round-trip), V staged
// bf16 hi/lo transposed [d][t] (mirrors proven K staging), epilogue dumps
// accO to LDS and reuses the r5/r7-proven (r2,sub) GroupNorm mapping (no
// shuffles). LDS ~71 KiB. grid (S/64, H), heavy-first dispatch.
// ---------------------------------------------------------------------------
__global__ __launch_bounds__(256) void retention_hybrid_kernel(
    const float* __restrict__ q_f, const float* __restrict__ k_f,
    const float* __restrict__ v_f, const float* __restrict__ gn_w,
    const float* __restrict__ gn_b, float* __restrict__ retn, int b) {
  __shared__ __align__(16) unsigned short Kh[64 * 136];   // 17 KiB
  __shared__ __align__(16) unsigned short Klo[64 * 136];  // 17 KiB
  __shared__ __align__(16) unsigned short Vh[64 * 72];    //  9 KiB [d][t]
  __shared__ __align__(16) unsigned short Vlo[64 * 72];   //  9 KiB
  __shared__ __align__(16) float Sc[64 * 68];             // 17 KiB
  __shared__ float gnred[64][8];                          //  2 KiB

  int tid = threadIdx.x;
  int w = tid >> 6;
  int lane = tid & 63, ln = lane & 15, quad = lane >> 4;
  int qt = (int)(gridDim.x - 1) - (int)blockIdx.x;  // heavy blocks first
  int h = blockIdx.y;
  int s0 = qt * 64;

  const float lo_c = -6.2383246250395075f, hi_c = -3.4657359027997265f;
  float gam = 1.f - __expf(lo_c + (hi_c - lo_c) * ((float)h * (1.f / 15.f)));
  float logg = __logf(gam);

  // Q fragments (A-layout), register hi/lo split. (proven r7)
  int sQ = s0 + w * 16 + ln;
  const float* qrow = q_f + ((size_t)h * S_ + sQ) * 128 + quad * 8;
  short8 qh[4], ql[4];
#pragma unroll
  for (int c = 0; c < 4; ++c) {
#pragma unroll
    for (int j = 0; j < 8; ++j) {
      float qv = qrow[c * 32 + j];
      unsigned short hh = f2bf(qv);
      qh[c][j] = (short)hh;
      ql[c][j] = (short)f2bf(qv - bf2f(hh));
    }
  }

  floatx4 accO[4];
#pragma unroll
  for (int i = 0; i < 4; ++i) accO[i] = (floatx4){0.f, 0.f, 0.f, 0.f};

  for (int kt = 0; kt <= qt; ++kt) {
    int t0 = kt * 64;
    __syncthreads();  // prev iteration's PV reads of Sc/Vh/Vlo done

    // stage K tile 64x128: fp32 -> split bf16 (proven r7)
#pragma unroll
    for (int i = 0; i < 8; ++i) {
      int cid = tid + i * 256;
      int rr = cid >> 5, c4 = (cid & 31) * 4;
      float4v kv = *reinterpret_cast<const float4v*>(
          k_f + ((size_t)h * S_ + t0 + rr) * 128 + c4);
      ushort4v khv, klv;
#pragma unroll
      for (int k = 0; k < 4; ++k) {
        unsigned short hh = f2bf(kv[k]);
        khv[k] = hh;
        klv[k] = f2bf(kv[k] - bf2f(hh));
      }
      *reinterpret_cast<ushort4v*>(&Kh[rr * 136 + c4]) = khv;
      *reinterpret_cast<ushort4v*>(&Klo[rr * 136 + c4]) = klv;
    }
    // stage V tile transposed [d][t]: fp32 -> split bf16
#pragma unroll
    for (int i = 0; i < 4; ++i) {
      int cid = tid + i * 256;
      int t = cid >> 4, d4 = (cid & 15) * 4;
      float4v vv = *reinterpret_cast<const float4v*>(
          v_f + ((size_t)h * S_ + t0 + t) * 64 + d4);
#pragma unroll
      for (int k = 0; k < 4; ++k) {
        unsigned short hh = f2bf(vv[k]);
        Vh[(d4 + k) * 72 + t] = hh;
        Vlo[(d4 + k) * 72 + t] = f2bf(vv[k] - bf2f(hh));
      }
    }
    __syncthreads();

    // QK^T split-MFMA (proven r7)
    floatx4 accS[4];
#pragma unroll
    for (int ns = 0; ns < 4; ++ns) {
      floatx4 a = (floatx4){0.f, 0.f, 0.f, 0.f};
#pragma unroll
      for (int ks = 0; ks < 4; ++ks) {
        int off = (ns * 16 + ln) * 136 + ks * 32 + quad * 8;
        short8 kh = *reinterpret_cast<const short8*>(&Kh[off]);
        short8 kl = *reinterpret_cast<const short8*>(&Klo[off]);
        a = __builtin_amdgcn_mfma_f32_16x16x32_bf16(qh[ks], kh, a, 0, 0, 0);
        a = __builtin_amdgcn_mfma_f32_16x16x32_bf16(ql[ks], kh, a, 0, 0, 0);
        a = __builtin_amdgcn_mfma_f32_16x16x32_bf16(qh[ks], kl, a, 0, 0, 0);
      }
      accS[ns] = a;
    }

    // decay + causal mask on C-layout -> fp32 Sc [row][t], stride 68 (proven)
    int prow = quad * 4;
#pragma unroll
    for (int ns = 0; ns < 4; ++ns) {
      int t = t0 + ns * 16 + ln;
#pragma unroll
      for (int rr = 0; rr < 4; ++rr) {
        int s = s0 + w * 16 + prow + rr;
        int diff = s - t;
        float v = accS[ns][rr];
        Sc[(w * 16 + prow + rr) * 68 + (ns * 16 + ln)] =
            (diff >= 0) ? v * __expf((float)diff * logg) : 0.f;
      }
    }
    __syncthreads();

    // PV split-MFMA: P A-frags from fp32 Sc, register hi/lo split.
#pragma unroll
    for (int ks = 0; ks < 2; ++ks) {
      const float* prow_p = &Sc[(w * 16 + ln) * 68 + ks * 32 + quad * 8];
      short8 ph, pl;
#pragma unroll
      for (int j = 0; j < 8; ++j) {
        float pv = prow_p[j];
        unsigned short hh = f2bf(pv);
        ph[j] = (short)hh;
        pl[j] = (short)f2bf(pv - bf2f(hh));
      }
#pragma unroll
      for (int ds = 0; ds < 4; ++ds) {
        int voff = (ds * 16 + ln) * 72 + ks * 32 + quad * 8;
        short8 vh = *reinterpret_cast<const short8*>(&Vh[voff]);
        short8 vl = *reinterpret_cast<const short8*>(&Vlo[voff]);
        accO[ds] = __builtin_amdgcn_mfma_f32_16x16x32_bf16(ph, vh, accO[ds], 0, 0, 0);
        accO[ds] = __builtin_amdgcn_mfma_f32_16x16x32_bf16(pl, vh, accO[ds], 0, 0, 0);
        accO[ds] = __builtin_amdgcn_mfma_f32_16x16x32_bf16(ph, vl, accO[ds], 0, 0, 0);
      }
    }
  }

  // Epilogue: dump accO (C-layout) into Sc as Out[row][d] fp32, then run the
  // proven (r2, sub) GroupNorm mapping from LDS.
  __syncthreads();  // all PV reads of Sc done
#pragma unroll
  for (int ds = 0; ds < 4; ++ds) {
#pragma unroll
    for (int rr = 0; rr < 4; ++rr) {
      Sc[(w * 16 + quad * 4 + rr) * 68 + ds * 16 + ln] = accO[ds][rr];
    }
  }
  __syncthreads();

  int r2 = tid >> 2;
  int sub = tid & 3;
  float a16[16];
#pragma unroll
  for (int i = 0; i < 16; ++i) a16[i] = Sc[r2 * 68 + sub * 16 + i];

  float psum = 0.f, psq = 0.f;
#pragma unroll
  for (int i = 0; i < 16; ++i) { psum += a16[i]; psq += a16[i] * a16[i]; }
  gnred[r2][sub] = psum;
  gnred[r2][4 + sub] = psq;
  __syncthreads();
  float sum = gnred[r2][0] + gnred[r2][1] + gnred[r2][2] + gnred[r2][3];
  float sq = gnred[r2][4] + gnred[r2][5] + gnred[r2][6] + gnred[r2][7];
  float mean = sum * (1.f / 64.f);
  float var = sq * (1.f / 64.f) - mean * mean;
  float rstd = rsqrtf(var + 1e-5f);

  size_t obase = ((size_t)(b * S_ + s0 + r2)) * HID_ + h * DH_ + sub * 16;
#pragma unroll
  for (int i = 0; i < 16; ++i) {
    float gw = gn_w[h * DH_ + sub * 16 + i];
    float gb = gn_b[h * DH_ + sub * 16 + i];
    retn[obase + i] = (a16[i] - mean) * rstd * gw + gb;
  }
}

// ---------------------------------------------------------------------------
// GEMM 1 (gate): unchanged, proven.
// ---------------------------------------------------------------------------
__global__ __launch_bounds__(256) void gemm_gate_kernel(
    const unsigned short* __restrict__ A, const unsigned short* __restrict__ Bt,
    const float* __restrict__ retn, unsigned short* __restrict__ pre_hi,
    unsigned short* __restrict__ pre_lo) {
  const int K = HID_;
  __shared__ __align__(16) unsigned short Al[128 * 56];
  __shared__ __align__(16) unsigned short Bl[128 * 56];

  int tid = threadIdx.x;
  int lane = tid & 63, ln = lane & 15, quad = lane >> 4;
  int w = tid >> 6, wm = w >> 1, wn = w & 1;
  int m0 = blockIdx.y * 128, n0 = blockIdx.x * 128;

  floatx4 acc[4][4];
#pragma unroll
  for (int i = 0; i < 4; ++i)
#pragma unroll
    for (int j = 0; j < 4; ++j) acc[i][j] = (floatx4){0.f, 0.f, 0.f, 0.f};

  for (int k0 = 0; k0 < K; k0 += 32) {
    __syncthreads();
#pragma unroll
    for (int i = 0; i < 2; ++i) {
      int cid = tid + i * 256;
      int r = cid >> 2, c8 = (cid & 3) * 8;
      *reinterpret_cast<ushort8*>(&Al[r * 56 + c8]) =
          *reinterpret_cast<const ushort8*>(A + (size_t)(m0 + r) * K + k0 + c8);
      *reinterpret_cast<ushort8*>(&Bl[r * 56 + c8]) =
          *reinterpret_cast<const ushort8*>(Bt + (size_t)(n0 + r) * K + k0 + c8);
    }
    __syncthreads();

    short8 af[4], bfr[4];
#pragma unroll
    for (int i = 0; i < 4; ++i) {
      af[i] = *reinterpret_cast<const short8*>(&Al[(wm * 64 + i * 16 + ln) * 56 + quad * 8]);
      bfr[i] = *reinterpret_cast<const short8*>(&Bl[(wn * 64 + i * 16 + ln) * 56 + quad * 8]);
    }
#pragma unroll
    for (int mi = 0; mi < 4; ++mi)
#pragma unroll
      for (int ni = 0; ni < 4; ++ni)
        acc[mi][ni] = __builtin_amdgcn_mfma_f32_16x16x32_bf16(af[mi], bfr[ni], acc[mi][ni], 0, 0, 0);
  }

#pragma unroll
  for (int mi = 0; mi < 4; ++mi) {
#pragma unroll
    for (int r = 0; r < 4; ++r) {
      int row = m0 + wm * 64 + mi * 16 + quad * 4 + r;
#pragma unroll
      for (int ni = 0; ni < 4; ++ni) {
        int col = n0 + wn * 64 + ni * 16 + ln;
        float g = acc[mi][ni][r];
        float val = g * (1.f / (1.f + __expf(-g))) + retn[(size_t)row * HID_ + col];
        unsigned short hh = f2bf(val);
        size_t oidx = (size_t)row * HID_ + col;
        pre_hi[oidx] = hh;
        pre_lo[oidx] = f2bf(val - bf2f(hh));
      }
    }
  }
}

// ---------------------------------------------------------------------------
// GEMM 2 (output): unchanged, proven.
// ---------------------------------------------------------------------------
__global__ __launch_bounds__(256) void gemm_out_kernel(
    const unsigned short* __restrict__ Ah, const unsigned short* __restrict__ Alo,
    const unsigned short* __restrict__ Bth, const unsigned short* __restrict__ Btlo,
    float* __restrict__ out_f) {
  const int K = HID_;
  __shared__ __align__(16) unsigned short AhS[128 * 56];
  __shared__ __align__(16) unsigned short AlS[128 * 56];
  __shared__ __align__(16) unsigned short BhS[128 * 56];
  __shared__ __align__(16) unsigned short BlS[128 * 56];

  int tid = threadIdx.x;
  int lane = tid & 63, ln = lane & 15, quad = lane >> 4;
  int w = tid >> 6, wm = w >> 1, wn = w & 1;
  int m0 = blockIdx.y * 128, n0 = blockIdx.x * 128;

  floatx4 acc[4][4];
#pragma unroll
  for (int i = 0; i < 4; ++i)
#pragma unroll
    for (int j = 0; j < 4; ++j) acc[i][j] = (floatx4){0.f, 0.f, 0.f, 0.f};

  for (int k0 = 0; k0 < K; k0 += 32) {
    __syncthreads();
#pragma unroll
    for (int i = 0; i < 2; ++i) {
      int cid = tid + i * 256;
      int r = cid >> 2, c8 = (cid & 3) * 8;
      size_t ga = (size_t)(m0 + r) * K + k0 + c8;
      size_t gb = (size_t)(n0 + r) * K + k0 + c8;
      *reinterpret_cast<ushort8*>(&AhS[r * 56 + c8]) = *reinterpret_cast<const ushort8*>(Ah + ga);
      *reinterpret_cast<ushort8*>(&AlS[r * 56 + c8]) = *reinterpret_cast<const ushort8*>(Alo + ga);
      *reinterpret_cast<ushort8*>(&BhS[r * 56 + c8]) = *reinterpret_cast<const ushort8*>(Bth + gb);
      *reinterpret_cast<ushort8*>(&BlS[r * 56 + c8]) = *reinterpret_cast<const ushort8*>(Btlo + gb);
    }
    __syncthreads();

    short8 afh[4], afl[4], bfh[4], bfl[4];
#pragma unroll
    for (int i = 0; i < 4; ++i) {
      int ao = (wm * 64 + i * 16 + ln) * 56 + quad * 8;
      int bo = (wn * 64 + i * 16 + ln) * 56 + quad * 8;
      afh[i] = *reinterpret_cast<const short8*>(&AhS[ao]);
      afl[i] = *reinterpret_cast<const short8*>(&AlS[ao]);
      bfh[i] = *reinterpret_cast<const short8*>(&BhS[bo]);
      bfl[i] = *reinterpret_cast<const short8*>(&BlS[bo]);
    }
#pragma unroll
    for (int mi = 0; mi < 4; ++mi)
#pragma unroll
      for (int ni = 0; ni < 4; ++ni) {
        floatx4 a = acc[mi][ni];
        a = __builtin_amdgcn_mfma_f32_16x16x32_bf16(afh[mi], bfh[ni], a, 0, 0, 0);
        a = __builtin_amdgcn_mfma_f32_16x16x32_bf16(afl[mi], bfh[ni], a, 0, 0, 0);
        a = __builtin_amdgcn_mfma_f32_16x16x32_bf16(afh[mi], bfl[ni], a, 0, 0, 0);
        acc[mi][ni] = a;
      }
  }

#pragma unroll
  for (int mi = 0; mi < 4; ++mi) {
#pragma unroll
    for (int r = 0; r < 4; ++r) {
      int row = m0 + wm * 64 + mi * 16 + quad * 4 + r;
#pragma unroll
      for (int ni = 0; ni < 4; ++ni) {
        int col = n0 + wn * 64 + ni * 16 + ln;
        out_f[(size_t)row * HID_ + col] = acc[mi][ni][r];
      }
    }
  }
}

// ---------------------------------------------------------------------------
extern "C" void kernel_launch(void* const* d_in, const int* in_sizes, int n_in,
                              void* d_out, int out_size, void* d_ws,
                              size_t ws_size, hipStream_t stream) {
  (void)in_sizes; (void)n_in; (void)out_size; (void)ws_size;
  const float* x = (const float*)d_in[0];
  const float* wq = (const float*)d_in[1];
  const float* bq = (const float*)d_in[2];
  const float* wk = (const float*)d_in[3];
  const float* bk = (const float*)d_in[4];
  const float* wv = (const float*)d_in[5];
  const float* theta = (const float*)d_in[6];
  const float* gn_w = (const float*)d_in[7];
  const float* gn_b = (const float*)d_in[8];
  const float* w1 = (const float*)d_in[9];
  const float* w2 = (const float*)d_in[10];

  const size_t MB = 1024 * 1024;
  char* ws = (char*)d_ws;
  unsigned short* x_bf   = (unsigned short*)(ws + 0 * MB);    //  8 MiB
  unsigned short* w1t    = (unsigned short*)(ws + 8 * MB);    //  2 MiB
  unsigned short* w2t_hi = (unsigned short*)(ws + 10 * MB);   //  2 MiB
  unsigned short* w2t_lo = (unsigned short*)(ws + 12 * MB);   //  2 MiB
  float*          q_f    = (float*)(ws + 14 * MB);            // 16 MiB (1 batch)
  float*          k_f    = (float*)(ws + 30 * MB);            // 16 MiB
  float*          v_f    = (float*)(ws + 46 * MB);            //  8 MiB
  float*          retn   = (float*)(ws + 54 * MB);            // 16 MiB (both batches)
  unsigned short* pre_hi = (unsigned short*)(ws + 14 * MB);   //  8 MiB (alias q_f)
  unsigned short* pre_lo = (unsigned short*)(ws + 22 * MB);   //  8 MiB
  float* out = (float*)d_out;

  convert_kernel<<<dim3(24576), 256, 0, stream>>>(x, w1, w2, x_bf, w1t, w2t_hi, w2t_lo);
  for (int b = 0; b < B_; ++b) {
    qkv_kernel<<<dim3(S_ / 64, H_), 256, 0, stream>>>(
        x, wq, bq, wk, bk, wv, theta, q_f, k_f, v_f, b);
    retention_hybrid_kernel<<<dim3(S_ / 64, H_), 256, 0, stream>>>(
        q_f, k_f, v_f, gn_w, gn_b, retn, b);
  }
  gemm_gate_kernel<<<dim3(HID_ / 128, (B_ * S_) / 128), 256, 0, stream>>>(
      x_bf, w1t, retn, pre_hi, pre_lo);
  gemm_out_kernel<<<dim3(HID_ / 128, (B_ * S_) / 128), 256, 0, stream>>>(
      pre_hi, pre_lo, w2t_hi, w2t_lo, out);
}